// Round 1
// baseline (1574.473 us; speedup 1.0000x reference)
//
#include <hip/hip_runtime.h>
#include <hip/hip_bf16.h>

// Problem: B=16,T=512,H=1024 -> N=M=8192 rows, H=1024.
// out[0] = mean_i [ log(sum_j exp(sim_ij/T)) - max_j sim_ij / T ]
// out[1] = 1 - mean_i dot(Tn[pos[i]], Tn[pos[i+1]])
// sim = normalized(h_s) @ normalized(h_t)^T, T = 0.07.

#define HDIM 1024
#define NROW 8192
#define TEMP_INV (1.0f / 0.07f)

typedef __attribute__((ext_vector_type(8))) short short8;   // 8 bf16 = 4 VGPRs
typedef __attribute__((ext_vector_type(4))) float float4v;  // MFMA C/D

// ws layout (bytes)
#define SN_OFF   ((size_t)0)                       // 16 MB bf16 S
#define TN_OFF   ((size_t)16777216)                // 16 MB bf16 T
#define POS_OFF  ((size_t)33554432)                // 8192 int
#define ACC_OFF  ((size_t)33587200)                // 2 floats: [0]=sum loss, [1]=sum nn_sim

static __device__ __forceinline__ unsigned short f2bf(float f) {
    unsigned u = __float_as_uint(f);
    u = (u + 0x7fffu + ((u >> 16) & 1u)) >> 16;    // RNE
    return (unsigned short)u;
}
static __device__ __forceinline__ float bf2f(short s) {
    return __uint_as_float(((unsigned)(unsigned short)s) << 16);
}

// ---------------- Phase 0: L2-normalize rows, write bf16; zero accumulators ----
__global__ void norm_kernel(const float* __restrict__ hs, const float* __restrict__ ht,
                            unsigned short* __restrict__ Sn, unsigned short* __restrict__ Tn,
                            float* __restrict__ acc) {
    int row = blockIdx.x;          // 0..16383
    int t = threadIdx.x;           // 256 threads, 4 floats each
    const float* in;
    unsigned short* out;
    if (row < NROW) { in = hs + (size_t)row * HDIM; out = Sn + (size_t)row * HDIM; }
    else            { in = ht + (size_t)(row - NROW) * HDIM; out = Tn + (size_t)(row - NROW) * HDIM; }

    float4v v = ((const float4v*)in)[t];
    float ss = v[0]*v[0] + v[1]*v[1] + v[2]*v[2] + v[3]*v[3];
    #pragma unroll
    for (int off = 1; off < 64; off <<= 1) ss += __shfl_xor(ss, off);
    __shared__ float red[4];
    if ((t & 63) == 0) red[t >> 6] = ss;
    __syncthreads();
    float tot = red[0] + red[1] + red[2] + red[3];
    float scale = 1.0f / fmaxf(sqrtf(tot), 1e-12f);

    unsigned r0 = f2bf(v[0]*scale), r1 = f2bf(v[1]*scale);
    unsigned r2 = f2bf(v[2]*scale), r3 = f2bf(v[3]*scale);
    uint2 pk; pk.x = r0 | (r1 << 16); pk.y = r2 | (r3 << 16);
    ((uint2*)out)[t] = pk;

    if (row == 0 && t == 0) { acc[0] = 0.0f; acc[1] = 0.0f; }
}

// ---------------- Phase 1: flash pass over sim = Sn @ Tn^T ---------------------
// Block: 16 source rows, 4 waves split the 8192 target cols (2048 each).
// A (16 rows x 1024) lives in 128 VGPRs per wave. B fragments streamed from
// global (Tn is 16 MB -> L2/L3 resident). Per-lane accumulation of sum-exp and
// max/argmax; cross-lane reduce + cross-wave LDS merge at the end.
__global__ __launch_bounds__(256, 2)
void flash_kernel(const unsigned short* __restrict__ Sn, const unsigned short* __restrict__ Tn,
                  int* __restrict__ pos_idx, float* __restrict__ acc) {
    const int wave = threadIdx.x >> 6;
    const int lane = threadIdx.x & 63;
    const int quad = lane >> 4;     // 0..3
    const int l16  = lane & 15;
    const int rbase = blockIdx.x * 16;

    // Load A fragments: lane holds A[m=l16][k = kstep*32 + quad*8 + j]
    short8 a[32];
    const short8* ap = (const short8*)(Sn + (size_t)(rbase + l16) * HDIM + quad * 8);
    #pragma unroll
    for (int k = 0; k < 32; ++k) a[k] = ap[k * 4];   // stride 32 bf16 = 4 short8

    float lsum[4] = {0.f, 0.f, 0.f, 0.f};
    float mx[4]   = {-2.f, -2.f, -2.f, -2.f};
    int   mi[4]   = {0, 0, 0, 0};

    const int cstart = wave * 2048;
    for (int c = cstart; c < cstart + 2048; c += 32) {
        float4v c0 = {0.f, 0.f, 0.f, 0.f};
        float4v c1 = {0.f, 0.f, 0.f, 0.f};
        const short8* bp0 = (const short8*)(Tn + (size_t)(c + l16) * HDIM + quad * 8);
        const short8* bp1 = (const short8*)(Tn + (size_t)(c + 16 + l16) * HDIM + quad * 8);
        #pragma unroll 8
        for (int k = 0; k < 32; ++k) {
            short8 b0 = bp0[k * 4];
            short8 b1 = bp1[k * 4];
            c0 = __builtin_amdgcn_mfma_f32_16x16x32_bf16(a[k], b0, c0, 0, 0, 0);
            c1 = __builtin_amdgcn_mfma_f32_16x16x32_bf16(a[k], b1, c1, 0, 0, 0);
        }
        // lane holds sim[rbase + quad*4 + r][c + l16] (c0) and [c+16+l16] (c1)
        #pragma unroll
        for (int r = 0; r < 4; ++r) {
            float v0 = c0[r], v1 = c1[r];
            lsum[r] += __expf(v0 * TEMP_INV) + __expf(v1 * TEMP_INV);
            if (v0 > mx[r]) { mx[r] = v0; mi[r] = c + l16; }
            if (v1 > mx[r]) { mx[r] = v1; mi[r] = c + 16 + l16; }
        }
    }

    // Reduce across the 16 lanes that share each row (within a quad group).
    #pragma unroll
    for (int r = 0; r < 4; ++r) {
        #pragma unroll
        for (int off = 1; off < 16; off <<= 1) {
            lsum[r] += __shfl_xor(lsum[r], off);
            float om = __shfl_xor(mx[r], off);
            int   oi = __shfl_xor(mi[r], off);
            if (om > mx[r] || (om == mx[r] && oi < mi[r])) { mx[r] = om; mi[r] = oi; }
        }
    }

    // Cross-wave merge via LDS: each wave holds partials for the same 16 rows.
    __shared__ float sl[4][16];
    __shared__ float sm[4][16];
    __shared__ int   si[4][16];
    if (l16 == 0) {
        #pragma unroll
        for (int r = 0; r < 4; ++r) {
            int row = quad * 4 + r;
            sl[wave][row] = lsum[r]; sm[wave][row] = mx[r]; si[wave][row] = mi[r];
        }
    }
    __syncthreads();
    if (threadIdx.x < 16) {
        int row = threadIdx.x;
        float l = 0.f; float m = -2.f; int idx = 0x7fffffff;
        #pragma unroll
        for (int w = 0; w < 4; ++w) {
            l += sl[w][row];
            float om = sm[w][row]; int oi = si[w][row];
            if (om > m || (om == m && oi < idx)) { m = om; idx = oi; }
        }
        pos_idx[rbase + row] = idx;
        float loss = logf(l) - m * TEMP_INV;   // -log p_i
        #pragma unroll
        for (int off = 1; off < 16; off <<= 1) loss += __shfl_xor(loss, off);
        if (row == 0) atomicAdd(acc + 0, loss);
    }
}

// ---------------- Phase 2: contextual consistency ------------------------------
// wave g computes dot(Tn[pos[g]], Tn[pos[g+1]]), g in [0, 8190].
__global__ void ctx_kernel(const unsigned short* __restrict__ Tn,
                           const int* __restrict__ pos, float* __restrict__ acc) {
    int g = (int)((blockIdx.x * blockDim.x + threadIdx.x) >> 6);
    if (g >= NROW - 1) return;
    int lane = threadIdx.x & 63;
    int ia = pos[g], ib = pos[g + 1];
    const short8* pa = (const short8*)(Tn + (size_t)ia * HDIM) + lane * 2;
    const short8* pb = (const short8*)(Tn + (size_t)ib * HDIM) + lane * 2;
    float s = 0.f;
    #pragma unroll
    for (int j = 0; j < 2; ++j) {
        short8 av = pa[j], bv = pb[j];
        #pragma unroll
        for (int e = 0; e < 8; ++e) s += bf2f(av[e]) * bf2f(bv[e]);
    }
    #pragma unroll
    for (int off = 1; off < 64; off <<= 1) s += __shfl_xor(s, off);
    if (lane == 0) atomicAdd(acc + 1, s);
}

// ---------------- Phase 3: finalize -------------------------------------------
__global__ void fin_kernel(const float* __restrict__ acc, float* __restrict__ out) {
    out[0] = acc[0] / (float)NROW;
    out[1] = 1.0f - acc[1] / (float)(NROW - 1);
}

extern "C" void kernel_launch(void* const* d_in, const int* in_sizes, int n_in,
                              void* d_out, int out_size, void* d_ws, size_t ws_size,
                              hipStream_t stream) {
    const float* hs = (const float*)d_in[0];
    const float* ht = (const float*)d_in[1];
    char* ws = (char*)d_ws;
    unsigned short* Sn = (unsigned short*)(ws + SN_OFF);
    unsigned short* Tn = (unsigned short*)(ws + TN_OFF);
    int*   pos = (int*)(ws + POS_OFF);
    float* acc = (float*)(ws + ACC_OFF);
    float* out = (float*)d_out;

    norm_kernel<<<2 * NROW, 256, 0, stream>>>(hs, ht, Sn, Tn, acc);
    flash_kernel<<<NROW / 16, 256, 0, stream>>>(Sn, Tn, pos, acc);
    ctx_kernel<<<(NROW + 3) / 4, 256, 0, stream>>>(Tn, pos, acc);
    fin_kernel<<<1, 1, 0, stream>>>(acc, out);
}

// Round 2
// 470.788 us; speedup vs baseline: 3.3443x; 3.3443x over previous
//
#include <hip/hip_runtime.h>
#include <hip/hip_bf16.h>
#include <stdint.h>

// B=16,T=512,H=1024 -> N=M=8192 rows, H=1024.
// out[0] = mean_i [ log(sum_j exp(sim_ij/T)) - max_j sim_ij / T ]
// out[1] = 1 - mean_i dot(Tn[pos[i]], Tn[pos[i+1]])

#define HDIM 1024
#define NROW 8192
#define TEMP_INV (1.0f / 0.07f)

typedef __attribute__((ext_vector_type(8))) short short8;   // 8 bf16 = 4 VGPRs
typedef __attribute__((ext_vector_type(4))) float float4v;  // MFMA C/D

// ws layout (bytes)
#define SN_OFF   ((size_t)0)                        // 16 MB bf16 S
#define TN_OFF   ((size_t)16777216)                 // 16 MB bf16 T
#define POS_OFF  ((size_t)33554432)                 // 8192 int
#define SUM_OFF  (POS_OFF + 32768)                  // 8192 float sum-exp
#define PMX_OFF  (SUM_OFF + 32768)                  // 8192 u64 packed (max,~idx)
#define ACC_OFF  (PMX_OFF + 65536)                  // 2 floats

static __device__ __forceinline__ unsigned short f2bf(float f) {
    unsigned u = __float_as_uint(f);
    u = (u + 0x7fffu + ((u >> 16) & 1u)) >> 16;     // RNE
    return (unsigned short)u;
}
static __device__ __forceinline__ float bf2f(short s) {
    return __uint_as_float(((unsigned)(unsigned short)s) << 16);
}

// async 16B global -> LDS (wave-uniform LDS base + lane*16 implicit)
static __device__ __forceinline__ void gload_lds16(const void* gptr, void* lptr) {
    __builtin_amdgcn_global_load_lds(
        (const __attribute__((address_space(1))) void*)gptr,
        (__attribute__((address_space(3))) void*)(uintptr_t)(uint32_t)(uintptr_t)lptr,
        16, 0, 0);
}

// ---------------- Phase 0: normalize rows -> bf16; zero reduction buffers ------
__global__ void norm_kernel(const float* __restrict__ hs, const float* __restrict__ ht,
                            unsigned short* __restrict__ Sn, unsigned short* __restrict__ Tn,
                            float* __restrict__ sumexp, unsigned long long* __restrict__ pmax,
                            float* __restrict__ acc) {
    int row = blockIdx.x;          // 0..16383
    int t = threadIdx.x;           // 256 threads, 4 floats each
    const float* in;
    unsigned short* out;
    if (row < NROW) { in = hs + (size_t)row * HDIM; out = Sn + (size_t)row * HDIM; }
    else            { in = ht + (size_t)(row - NROW) * HDIM; out = Tn + (size_t)(row - NROW) * HDIM; }

    float4v v = ((const float4v*)in)[t];
    float ss = v[0]*v[0] + v[1]*v[1] + v[2]*v[2] + v[3]*v[3];
    #pragma unroll
    for (int off = 1; off < 64; off <<= 1) ss += __shfl_xor(ss, off);
    __shared__ float red[4];
    if ((t & 63) == 0) red[t >> 6] = ss;
    __syncthreads();
    float tot = red[0] + red[1] + red[2] + red[3];
    float scale = 1.0f / fmaxf(sqrtf(tot), 1e-12f);

    unsigned r0 = f2bf(v[0]*scale), r1 = f2bf(v[1]*scale);
    unsigned r2 = f2bf(v[2]*scale), r3 = f2bf(v[3]*scale);
    uint2 pk; pk.x = r0 | (r1 << 16); pk.y = r2 | (r3 << 16);
    ((uint2*)out)[t] = pk;

    if (row < NROW) {
        if (t == 0) sumexp[row] = 0.0f;
        if (t == 1) pmax[row] = 0ull;
    }
    if (row == 0 && t == 2) { acc[0] = 0.0f; acc[1] = 0.0f; }
}

// ---------------- Phase 1: tiled MFMA flash pass over sim = Sn @ Tn^T ----------
// Grid 64x64 blocks of 128(rows)x128(cols). 4 waves 2x2, each 64x64 via 4x4
// grid of 16x16x32 MFMAs. A/B staged to LDS in MFMA-fragment order (1KB blocks,
// lane-contiguous) via global_load_lds width 16 -> conflict-free ds_read_b128.
__global__ __launch_bounds__(256, 2)
void flash_kernel(const unsigned short* __restrict__ Sn,
                  const unsigned short* __restrict__ Tn,
                  float* __restrict__ sumexp,
                  unsigned long long* __restrict__ pmax) {
    __shared__ __align__(16) char As[16384];
    __shared__ __align__(16) char Bs[16384];
    const int t = threadIdx.x;
    const int wave = t >> 6, lane = t & 63;
    const int quad = lane >> 4, l16 = lane & 15;
    const int rbase = (int)(blockIdx.x & 63) * 128;
    const int cbase = (int)(blockIdx.x >> 6) * 128;

    // Staging: chunk b = i*4+wave (b = fragment id = rowgrp*2 + kstep).
    // rowgrp = i*2 + (wave>>1), kstep = wave&1.
    // lane covers row = rg*16 + (lane&15), k = ks*32 + (lane>>4)*8 (16B).
    const int kq = (wave & 1) * 32 + quad * 8;
    const char* ga[4]; const char* gb[4];
    #pragma unroll
    for (int i = 0; i < 4; ++i) {
        int r = rbase + (wave >> 1) * 16 + i * 32 + l16;
        int c = cbase + (wave >> 1) * 16 + i * 32 + l16;
        ga[i] = (const char*)(Sn + (size_t)r * HDIM + kq);
        gb[i] = (const char*)(Tn + (size_t)c * HDIM + kq);
    }

    float4v acc[4][4];
    #pragma unroll
    for (int i = 0; i < 4; ++i)
        #pragma unroll
        for (int j = 0; j < 4; ++j) acc[i][j] = (float4v){0.f, 0.f, 0.f, 0.f};

    const int wm = (wave & 1) * 64, wn = (wave >> 1) * 64;

    for (int kb = 0; kb < HDIM; kb += 64) {
        #pragma unroll
        for (int i = 0; i < 4; ++i) {
            gload_lds16(ga[i], As + (i * 4 + wave) * 1024);
            gload_lds16(gb[i], Bs + (i * 4 + wave) * 1024);
            ga[i] += 128; gb[i] += 128;   // advance 64 bf16 in k
        }
        __syncthreads();
        #pragma unroll
        for (int ks = 0; ks < 2; ++ks) {
            short8 af[4], bf[4];
            #pragma unroll
            for (int i = 0; i < 4; ++i) {
                af[i] = *(const short8*)(As + ((wm / 16 + i) * 2 + ks) * 1024 + lane * 16);
                bf[i] = *(const short8*)(Bs + ((wn / 16 + i) * 2 + ks) * 1024 + lane * 16);
            }
            #pragma unroll
            for (int i = 0; i < 4; ++i)
                #pragma unroll
                for (int j = 0; j < 4; ++j)
                    acc[i][j] = __builtin_amdgcn_mfma_f32_16x16x32_bf16(af[i], bf[j], acc[i][j], 0, 0, 0);
        }
        __syncthreads();
    }

    // Epilogue: lane holds sim[rbase+wm+i*16+quad*4+r][cbase+wn+j*16+l16]
    #pragma unroll
    for (int i = 0; i < 4; ++i) {
        #pragma unroll
        for (int r = 0; r < 4; ++r) {
            float se = 0.f; float mx = -2.f; int mi = 0x7fffffff;
            #pragma unroll
            for (int j = 0; j < 4; ++j) {
                float v = acc[i][j][r];
                se += __expf(v * TEMP_INV);
                int col = cbase + wn + j * 16 + l16;
                if (v > mx || (v == mx && col < mi)) { mx = v; mi = col; }
            }
            #pragma unroll
            for (int off = 1; off < 16; off <<= 1) {
                se += __shfl_xor(se, off);
                float om = __shfl_xor(mx, off);
                int oi = __shfl_xor(mi, off);
                if (om > mx || (om == mx && oi < mi)) { mx = om; mi = oi; }
            }
            if (l16 == 0) {
                int row = rbase + wm + i * 16 + quad * 4 + r;
                atomicAdd(&sumexp[row], se);
                unsigned long long pk =
                    ((unsigned long long)__float_as_uint(mx + 2.0f) << 32)
                    | (unsigned long long)(0xffffffffu - (unsigned)mi);
                atomicMax(&pmax[row], pk);
            }
        }
    }
}

// ---------------- Phase 2: per-row loss + pos extraction -----------------------
__global__ void rowloss_kernel(const float* __restrict__ sumexp,
                               const unsigned long long* __restrict__ pmax,
                               int* __restrict__ pos, float* __restrict__ acc) {
    int r = blockIdx.x * 256 + threadIdx.x;
    unsigned long long p = pmax[r];
    float mx = __uint_as_float((unsigned)(p >> 32)) - 2.0f;
    pos[r] = (int)(0xffffffffu - (unsigned)(p & 0xffffffffu));
    float loss = logf(sumexp[r]) - mx * TEMP_INV;
    #pragma unroll
    for (int off = 1; off < 64; off <<= 1) loss += __shfl_xor(loss, off);
    __shared__ float red[4];
    if ((threadIdx.x & 63) == 0) red[threadIdx.x >> 6] = loss;
    __syncthreads();
    if (threadIdx.x == 0) atomicAdd(acc + 0, red[0] + red[1] + red[2] + red[3]);
}

// ---------------- Phase 3: contextual consistency ------------------------------
__global__ void ctx_kernel(const unsigned short* __restrict__ Tn,
                           const int* __restrict__ pos, float* __restrict__ acc) {
    int g = (int)((blockIdx.x * blockDim.x + threadIdx.x) >> 6);
    if (g >= NROW - 1) return;
    int lane = threadIdx.x & 63;
    int ia = pos[g], ib = pos[g + 1];
    const short8* pa = (const short8*)(Tn + (size_t)ia * HDIM) + lane * 2;
    const short8* pb = (const short8*)(Tn + (size_t)ib * HDIM) + lane * 2;
    float s = 0.f;
    #pragma unroll
    for (int j = 0; j < 2; ++j) {
        short8 av = pa[j], bv = pb[j];
        #pragma unroll
        for (int e = 0; e < 8; ++e) s += bf2f(av[e]) * bf2f(bv[e]);
    }
    #pragma unroll
    for (int off = 1; off < 64; off <<= 1) s += __shfl_xor(s, off);
    if (lane == 0) atomicAdd(acc + 1, s);
}

// ---------------- Phase 4: finalize -------------------------------------------
__global__ void fin_kernel(const float* __restrict__ acc, float* __restrict__ out) {
    out[0] = acc[0] / (float)NROW;
    out[1] = 1.0f - acc[1] / (float)(NROW - 1);
}

extern "C" void kernel_launch(void* const* d_in, const int* in_sizes, int n_in,
                              void* d_out, int out_size, void* d_ws, size_t ws_size,
                              hipStream_t stream) {
    const float* hs = (const float*)d_in[0];
    const float* ht = (const float*)d_in[1];
    char* ws = (char*)d_ws;
    unsigned short* Sn = (unsigned short*)(ws + SN_OFF);
    unsigned short* Tn = (unsigned short*)(ws + TN_OFF);
    int*   pos = (int*)(ws + POS_OFF);
    float* sumexp = (float*)(ws + SUM_OFF);
    unsigned long long* pmax = (unsigned long long*)(ws + PMX_OFF);
    float* acc = (float*)(ws + ACC_OFF);
    float* out = (float*)d_out;

    norm_kernel<<<2 * NROW, 256, 0, stream>>>(hs, ht, Sn, Tn, sumexp, pmax, acc);
    flash_kernel<<<64 * 64, 256, 0, stream>>>(Sn, Tn, sumexp, pmax);
    rowloss_kernel<<<NROW / 256, 256, 0, stream>>>(sumexp, pmax, pos, acc);
    ctx_kernel<<<(NROW + 3) / 4, 256, 0, stream>>>(Tn, pos, acc);
    fin_kernel<<<1, 1, 0, stream>>>(acc, out);
}

// Round 3
// 340.839 us; speedup vs baseline: 4.6194x; 1.3813x over previous
//
#include <hip/hip_runtime.h>
#include <hip/hip_bf16.h>
#include <stdint.h>

// B=16,T=512,H=1024 -> N=M=8192 rows, H=1024.
// out[0] = mean_i [ log(sum_j exp(sim_ij/T)) - max_j sim_ij / T ]
// out[1] = 1 - mean_i dot(Tn[pos[i]], Tn[pos[i+1]])

#define HDIM 1024
#define NROW 8192
#define TEMP_INV (1.0f / 0.07f)

typedef __attribute__((ext_vector_type(8))) short short8;   // 8 bf16 = 4 VGPRs
typedef __attribute__((ext_vector_type(4))) float float4v;  // MFMA C/D

// ws layout (bytes)
#define SN_OFF   ((size_t)0)                        // 16 MB bf16 S
#define TN_OFF   ((size_t)16777216)                 // 16 MB bf16 T
#define POS_OFF  ((size_t)33554432)                 // 8192 int
#define SUM_OFF  (POS_OFF + 32768)                  // 8192 float sum-exp
#define PMX_OFF  (SUM_OFF + 32768)                  // 8192 u64 packed (max,~idx)
#define ACC_OFF  (PMX_OFF + 65536)                  // 2 floats

static __device__ __forceinline__ unsigned short f2bf(float f) {
    unsigned u = __float_as_uint(f);
    u = (u + 0x7fffu + ((u >> 16) & 1u)) >> 16;     // RNE
    return (unsigned short)u;
}
static __device__ __forceinline__ float bf2f(short s) {
    return __uint_as_float(((unsigned)(unsigned short)s) << 16);
}

// async 16B global -> LDS (wave-uniform LDS base + lane*16 implicit)
static __device__ __forceinline__ void gload_lds16(const void* gptr, void* lptr) {
    __builtin_amdgcn_global_load_lds(
        (const __attribute__((address_space(1))) void*)gptr,
        (__attribute__((address_space(3))) void*)(uintptr_t)(uint32_t)(uintptr_t)lptr,
        16, 0, 0);
}

// ---------------- Phase 0: normalize rows -> bf16 (1 wave per row) ------------
__global__ __launch_bounds__(256)
void norm_kernel(const float* __restrict__ hs, const float* __restrict__ ht,
                 unsigned short* __restrict__ Sn, unsigned short* __restrict__ Tn,
                 float* __restrict__ sumexp, unsigned long long* __restrict__ pmax,
                 float* __restrict__ acc) {
    const int wave = threadIdx.x >> 6, lane = threadIdx.x & 63;
    const int row = blockIdx.x * 4 + wave;          // 0..16383
    const float* in;
    unsigned short* out;
    if (row < NROW) { in = hs + (size_t)row * HDIM; out = Sn + (size_t)row * HDIM; }
    else            { in = ht + (size_t)(row - NROW) * HDIM; out = Tn + (size_t)(row - NROW) * HDIM; }

    float4v v[4];
    float ss = 0.f;
    #pragma unroll
    for (int j = 0; j < 4; ++j) {
        v[j] = ((const float4v*)in)[j * 64 + lane];
        ss += v[j][0]*v[j][0] + v[j][1]*v[j][1] + v[j][2]*v[j][2] + v[j][3]*v[j][3];
    }
    #pragma unroll
    for (int off = 1; off < 64; off <<= 1) ss += __shfl_xor(ss, off);
    float scale = 1.0f / fmaxf(sqrtf(ss), 1e-12f);

    #pragma unroll
    for (int j = 0; j < 4; ++j) {
        unsigned r0 = f2bf(v[j][0]*scale), r1 = f2bf(v[j][1]*scale);
        unsigned r2 = f2bf(v[j][2]*scale), r3 = f2bf(v[j][3]*scale);
        uint2 pk; pk.x = r0 | (r1 << 16); pk.y = r2 | (r3 << 16);
        ((uint2*)out)[j * 64 + lane] = pk;
    }

    if (row < NROW) {
        if (lane == 0) sumexp[row] = 0.0f;
        if (lane == 1) pmax[row] = 0ull;
    }
    if (row == 0 && lane == 2) { acc[0] = 0.0f; acc[1] = 0.0f; }
}

// ---------------- Phase 1: tiled MFMA flash pass over sim = Sn @ Tn^T ----------
// Grid 32x64 blocks of 256(rows)x128(cols). 8 waves in 4x2 layout, each 64x64
// via 4x4 grid of 16x16x32 MFMAs. A/B staged to LDS in MFMA-fragment order
// (1KB lane-contiguous chunks) via global_load_lds w=16 -> conflict-free
// ds_read_b128. Epilogue: 16-lane butterfly, LDS merge of the two column
// halves, then atomics (256 pairs/block, spread over 8192 row addresses).
__global__ __launch_bounds__(512, 4)
void flash_kernel(const unsigned short* __restrict__ Sn,
                  const unsigned short* __restrict__ Tn,
                  float* __restrict__ sumexp,
                  unsigned long long* __restrict__ pmax) {
    __shared__ __align__(16) char As[32768];        // 32 chunks of 1KB
    __shared__ __align__(16) char Bs[16384];        // 16 chunks of 1KB
    const int t = threadIdx.x;
    const int wave = t >> 6, lane = t & 63;
    const int quad = lane >> 4, l16 = lane & 15;
    const int rbase = (int)(blockIdx.x & 31) * 256;
    const int cbase = (int)(blockIdx.x >> 5) * 128;

    // Staging: A chunk ca = rg*2+ks (rg 0..15, ks 0..1): wave w -> ca in
    // {4w..4w+3}. B chunk cb = cg*2+ks (cg 0..7): wave w -> {2w, 2w+1}.
    // Within a chunk lane covers row rg*16+l16, k = ks*32 + quad*8 (16B).
    const char* ga[4]; const char* gb[2];
    #pragma unroll
    for (int i = 0; i < 4; ++i) {
        int ca = wave * 4 + i, rg = ca >> 1, ks = ca & 1;
        ga[i] = (const char*)(Sn + (size_t)(rbase + rg * 16 + l16) * HDIM + ks * 32 + quad * 8);
    }
    #pragma unroll
    for (int i = 0; i < 2; ++i) {
        int cb = wave * 2 + i, cg = cb >> 1, ks = cb & 1;
        gb[i] = (const char*)(Tn + (size_t)(cbase + cg * 16 + l16) * HDIM + ks * 32 + quad * 8);
    }

    float4v acc[4][4];
    #pragma unroll
    for (int i = 0; i < 4; ++i)
        #pragma unroll
        for (int j = 0; j < 4; ++j) acc[i][j] = (float4v){0.f, 0.f, 0.f, 0.f};

    const int wm = (wave & 3) * 64, wn = (wave >> 2) * 64;

    for (int kb = 0; kb < HDIM; kb += 64) {
        #pragma unroll
        for (int i = 0; i < 4; ++i) {
            gload_lds16(ga[i], As + (wave * 4 + i) * 1024);
            ga[i] += 128;                           // advance 64 bf16 in k
        }
        #pragma unroll
        for (int i = 0; i < 2; ++i) {
            gload_lds16(gb[i], Bs + (wave * 2 + i) * 1024);
            gb[i] += 128;
        }
        __syncthreads();
        #pragma unroll
        for (int ks = 0; ks < 2; ++ks) {
            short8 af[4], bf[4];
            #pragma unroll
            for (int i = 0; i < 4; ++i) {
                af[i] = *(const short8*)(As + ((wm / 16 + i) * 2 + ks) * 1024 + lane * 16);
                bf[i] = *(const short8*)(Bs + ((wn / 16 + i) * 2 + ks) * 1024 + lane * 16);
            }
            #pragma unroll
            for (int i = 0; i < 4; ++i)
                #pragma unroll
                for (int j = 0; j < 4; ++j)
                    acc[i][j] = __builtin_amdgcn_mfma_f32_16x16x32_bf16(af[i], bf[j], acc[i][j], 0, 0, 0);
        }
        __syncthreads();
    }

    // Epilogue. lane holds sim[rbase+wm+i*16+quad*4+r][cbase+wn+j*16+l16].
    float* sL = (float*)As;                         // [256]
    unsigned long long* sP = (unsigned long long*)(As + 1024);  // [256]
    float se_v[4][4]; unsigned long long pk_v[4][4];
    #pragma unroll
    for (int i = 0; i < 4; ++i) {
        #pragma unroll
        for (int r = 0; r < 4; ++r) {
            float se = 0.f; float mx = -2.f; int mi = 0x7fffffff;
            #pragma unroll
            for (int j = 0; j < 4; ++j) {
                float v = acc[i][j][r];
                se += __expf(v * TEMP_INV);
                int col = cbase + wn + j * 16 + l16;
                if (v > mx || (v == mx && col < mi)) { mx = v; mi = col; }
            }
            #pragma unroll
            for (int off = 1; off < 16; off <<= 1) {
                se += __shfl_xor(se, off);
                float om = __shfl_xor(mx, off);
                int oi = __shfl_xor(mi, off);
                if (om > mx || (om == mx && oi < mi)) { mx = om; mi = oi; }
            }
            se_v[i][r] = se;
            pk_v[i][r] = ((unsigned long long)__float_as_uint(mx + 2.0f) << 32)
                         | (unsigned long long)(0xffffffffu - (unsigned)mi);
        }
    }
    // waves 0-3 (wn=0 half) publish; waves 4-7 merge + atomic.
    if (wave < 4 && l16 == 0) {
        #pragma unroll
        for (int i = 0; i < 4; ++i)
            #pragma unroll
            for (int r = 0; r < 4; ++r) {
                int rl = wm + i * 16 + quad * 4 + r;
                sL[rl] = se_v[i][r]; sP[rl] = pk_v[i][r];
            }
    }
    __syncthreads();
    if (wave >= 4 && l16 == 0) {
        #pragma unroll
        for (int i = 0; i < 4; ++i)
            #pragma unroll
            for (int r = 0; r < 4; ++r) {
                int rl = wm + i * 16 + quad * 4 + r;
                float se = se_v[i][r] + sL[rl];
                unsigned long long pk = pk_v[i][r];
                unsigned long long po = sP[rl];
                if (po > pk) pk = po;
                atomicAdd(&sumexp[rbase + rl], se);
                atomicMax(&pmax[rbase + rl], pk);
            }
    }
}

// ---------------- Phase 2: per-row loss + pos extraction -----------------------
__global__ void rowloss_kernel(const float* __restrict__ sumexp,
                               const unsigned long long* __restrict__ pmax,
                               int* __restrict__ pos, float* __restrict__ acc) {
    int r = blockIdx.x * 256 + threadIdx.x;
    unsigned long long p = pmax[r];
    float mx = __uint_as_float((unsigned)(p >> 32)) - 2.0f;
    pos[r] = (int)(0xffffffffu - (unsigned)(p & 0xffffffffu));
    float loss = logf(sumexp[r]) - mx * TEMP_INV;
    #pragma unroll
    for (int off = 1; off < 64; off <<= 1) loss += __shfl_xor(loss, off);
    __shared__ float red[4];
    if ((threadIdx.x & 63) == 0) red[threadIdx.x >> 6] = loss;
    __syncthreads();
    if (threadIdx.x == 0) atomicAdd(acc + 0, red[0] + red[1] + red[2] + red[3]);
}

// ---------------- Phase 3: contextual consistency ------------------------------
// 256 blocks x 4 waves, grid-stride over 8191 pairs, one atomic per block.
__global__ __launch_bounds__(256)
void ctx_kernel(const unsigned short* __restrict__ Tn,
                const int* __restrict__ pos, float* __restrict__ acc) {
    const int wave = threadIdx.x >> 6, lane = threadIdx.x & 63;
    const int wid = blockIdx.x * 4 + wave;          // 0..1023
    float s = 0.f;
    for (int g = wid; g < NROW - 1; g += 1024) {
        int ia = pos[g], ib = pos[g + 1];
        const short8* pa = (const short8*)(Tn + (size_t)ia * HDIM) + lane * 2;
        const short8* pb = (const short8*)(Tn + (size_t)ib * HDIM) + lane * 2;
        #pragma unroll
        for (int j = 0; j < 2; ++j) {
            short8 av = pa[j], bv = pb[j];
            #pragma unroll
            for (int e = 0; e < 8; ++e) s += bf2f(av[e]) * bf2f(bv[e]);
        }
    }
    #pragma unroll
    for (int off = 1; off < 64; off <<= 1) s += __shfl_xor(s, off);
    __shared__ float red[4];
    if (lane == 0) red[wave] = s;
    __syncthreads();
    if (threadIdx.x == 0) atomicAdd(acc + 1, red[0] + red[1] + red[2] + red[3]);
}

// ---------------- Phase 4: finalize -------------------------------------------
__global__ void fin_kernel(const float* __restrict__ acc, float* __restrict__ out) {
    out[0] = acc[0] / (float)NROW;
    out[1] = 1.0f - acc[1] / (float)(NROW - 1);
}

extern "C" void kernel_launch(void* const* d_in, const int* in_sizes, int n_in,
                              void* d_out, int out_size, void* d_ws, size_t ws_size,
                              hipStream_t stream) {
    const float* hs = (const float*)d_in[0];
    const float* ht = (const float*)d_in[1];
    char* ws = (char*)d_ws;
    unsigned short* Sn = (unsigned short*)(ws + SN_OFF);
    unsigned short* Tn = (unsigned short*)(ws + TN_OFF);
    int*   pos = (int*)(ws + POS_OFF);
    float* sumexp = (float*)(ws + SUM_OFF);
    unsigned long long* pmax = (unsigned long long*)(ws + PMX_OFF);
    float* acc = (float*)(ws + ACC_OFF);
    float* out = (float*)d_out;

    norm_kernel<<<4096, 256, 0, stream>>>(hs, ht, Sn, Tn, sumexp, pmax, acc);
    flash_kernel<<<32 * 64, 512, 0, stream>>>(Sn, Tn, sumexp, pmax);
    rowloss_kernel<<<NROW / 256, 256, 0, stream>>>(sumexp, pmax, pos, acc);
    ctx_kernel<<<256, 256, 0, stream>>>(Tn, pos, acc);
    fin_kernel<<<1, 1, 0, stream>>>(acc, out);
}

// Round 4
// 338.831 us; speedup vs baseline: 4.6468x; 1.0059x over previous
//
#include <hip/hip_runtime.h>
#include <hip/hip_bf16.h>
#include <stdint.h>

// B=16,T=512,H=1024 -> N=M=8192 rows, H=1024.
// out[0] = mean_i [ log(sum_j exp(sim_ij/T)) - max_j sim_ij / T ]
// out[1] = 1 - mean_i dot(Tn[pos[i]], Tn[pos[i+1]])

#define HDIM 1024
#define NROW 8192
#define TEMP_INV (1.0f / 0.07f)

typedef __attribute__((ext_vector_type(8))) short short8;   // 8 bf16 = 4 VGPRs
typedef __attribute__((ext_vector_type(4))) float float4v;  // MFMA C/D

// ws layout (bytes)
#define SN_OFF   ((size_t)0)                        // 16 MB bf16 S
#define TN_OFF   ((size_t)16777216)                 // 16 MB bf16 T
#define POS_OFF  ((size_t)33554432)                 // 8192 int
#define SUM_OFF  (POS_OFF + 32768)                  // 8192 float sum-exp
#define PMX_OFF  (SUM_OFF + 32768)                  // 8192 u64 packed (max,~idx)
#define ACC_OFF  (PMX_OFF + 65536)                  // 2 floats

static __device__ __forceinline__ unsigned short f2bf(float f) {
    unsigned u = __float_as_uint(f);
    u = (u + 0x7fffu + ((u >> 16) & 1u)) >> 16;     // RNE
    return (unsigned short)u;
}
static __device__ __forceinline__ float bf2f(short s) {
    return __uint_as_float(((unsigned)(unsigned short)s) << 16);
}

// async 16B global -> LDS (wave-uniform LDS base + lane*16 implicit)
static __device__ __forceinline__ void gload_lds16(const void* gptr, void* lptr) {
    __builtin_amdgcn_global_load_lds(
        (const __attribute__((address_space(1))) void*)gptr,
        (__attribute__((address_space(3))) void*)(uintptr_t)(uint32_t)(uintptr_t)lptr,
        16, 0, 0);
}

// ---------------- Phase 0: normalize rows -> bf16 (1 wave per row) ------------
__global__ __launch_bounds__(256)
void norm_kernel(const float* __restrict__ hs, const float* __restrict__ ht,
                 unsigned short* __restrict__ Sn, unsigned short* __restrict__ Tn,
                 float* __restrict__ sumexp, unsigned long long* __restrict__ pmax,
                 float* __restrict__ acc) {
    const int wave = threadIdx.x >> 6, lane = threadIdx.x & 63;
    const int row = blockIdx.x * 4 + wave;          // 0..16383
    const float* in;
    unsigned short* out;
    if (row < NROW) { in = hs + (size_t)row * HDIM; out = Sn + (size_t)row * HDIM; }
    else            { in = ht + (size_t)(row - NROW) * HDIM; out = Tn + (size_t)(row - NROW) * HDIM; }

    float4v v[4];
    float ss = 0.f;
    #pragma unroll
    for (int j = 0; j < 4; ++j) {
        v[j] = ((const float4v*)in)[j * 64 + lane];
        ss += v[j][0]*v[j][0] + v[j][1]*v[j][1] + v[j][2]*v[j][2] + v[j][3]*v[j][3];
    }
    #pragma unroll
    for (int off = 1; off < 64; off <<= 1) ss += __shfl_xor(ss, off);
    float scale = 1.0f / fmaxf(sqrtf(ss), 1e-12f);

    #pragma unroll
    for (int j = 0; j < 4; ++j) {
        unsigned r0 = f2bf(v[j][0]*scale), r1 = f2bf(v[j][1]*scale);
        unsigned r2 = f2bf(v[j][2]*scale), r3 = f2bf(v[j][3]*scale);
        uint2 pk; pk.x = r0 | (r1 << 16); pk.y = r2 | (r3 << 16);
        ((uint2*)out)[j * 64 + lane] = pk;
    }

    if (row < NROW) {
        if (lane == 0) sumexp[row] = 0.0f;
        if (lane == 1) pmax[row] = 0ull;
    }
    if (row == 0 && lane == 2) { acc[0] = 0.0f; acc[1] = 0.0f; }
}

// ---------------- Phase 1: tiled MFMA flash pass over sim = Sn @ Tn^T ----------
// 2048 blocks of 256(rows)x128(cols), 8 waves (4x2), each 64x64 via 4x4 grid of
// 16x16x32 MFMAs. XCD-aware swizzle: xcd = bid%8 (HW round-robin heuristic);
// each XCD owns 4 fixed row-bands (A working set 2 MB -> L2-resident), and the
// 4 blocks sharing a B-strip (bids 32*cb+8q+xcd) dispatch within a 24-bid
// window on the same XCD -> B fetched from L3 once per group. Converts ~1.5 GB
// of L3 traffic into per-XCD L2 hits.
__global__ __launch_bounds__(512, 4)
void flash_kernel(const unsigned short* __restrict__ Sn,
                  const unsigned short* __restrict__ Tn,
                  float* __restrict__ sumexp,
                  unsigned long long* __restrict__ pmax) {
    __shared__ __align__(16) char As[32768];        // 32 chunks of 1KB
    __shared__ __align__(16) char Bs[16384];        // 16 chunks of 1KB
    const int t = threadIdx.x;
    const int wave = t >> 6, lane = t & 63;
    const int quad = lane >> 4, l16 = lane & 15;

    const int bid = (int)blockIdx.x;                // 0..2047
    const int xcd = bid & 7;
    const int j0  = bid >> 3;                       // 0..255
    const int rb  = xcd * 4 + (j0 & 3);             // 0..31
    const int cb  = j0 >> 2;                        // 0..63
    const int rbase = rb * 256;
    const int cbase = cb * 128;

    // Staging: A chunk ca = rg*2+ks (rg 0..15, ks 0..1): wave w -> ca in
    // {4w..4w+3}. B chunk cb2 = cg*2+ks (cg 0..7): wave w -> {2w, 2w+1}.
    // Within a chunk lane covers row rg*16+l16, k = ks*32 + quad*8 (16B).
    const char* ga[4]; const char* gb[2];
    #pragma unroll
    for (int i = 0; i < 4; ++i) {
        int ca = wave * 4 + i, rg = ca >> 1, ks = ca & 1;
        ga[i] = (const char*)(Sn + (size_t)(rbase + rg * 16 + l16) * HDIM + ks * 32 + quad * 8);
    }
    #pragma unroll
    for (int i = 0; i < 2; ++i) {
        int cc = wave * 2 + i, cg = cc >> 1, ks = cc & 1;
        gb[i] = (const char*)(Tn + (size_t)(cbase + cg * 16 + l16) * HDIM + ks * 32 + quad * 8);
    }

    float4v acc[4][4];
    #pragma unroll
    for (int i = 0; i < 4; ++i)
        #pragma unroll
        for (int j = 0; j < 4; ++j) acc[i][j] = (float4v){0.f, 0.f, 0.f, 0.f};

    const int wm = (wave & 3) * 64, wn = (wave >> 2) * 64;

    for (int kb = 0; kb < HDIM; kb += 64) {
        #pragma unroll
        for (int i = 0; i < 4; ++i) {
            gload_lds16(ga[i], As + (wave * 4 + i) * 1024);
            ga[i] += 128;                           // advance 64 bf16 in k
        }
        #pragma unroll
        for (int i = 0; i < 2; ++i) {
            gload_lds16(gb[i], Bs + (wave * 2 + i) * 1024);
            gb[i] += 128;
        }
        __syncthreads();
        #pragma unroll
        for (int ks = 0; ks < 2; ++ks) {
            short8 af[4], bf[4];
            #pragma unroll
            for (int i = 0; i < 4; ++i) {
                af[i] = *(const short8*)(As + ((wm / 16 + i) * 2 + ks) * 1024 + lane * 16);
                bf[i] = *(const short8*)(Bs + ((wn / 16 + i) * 2 + ks) * 1024 + lane * 16);
            }
            #pragma unroll
            for (int i = 0; i < 4; ++i)
                #pragma unroll
                for (int j = 0; j < 4; ++j)
                    acc[i][j] = __builtin_amdgcn_mfma_f32_16x16x32_bf16(af[i], bf[j], acc[i][j], 0, 0, 0);
        }
        __syncthreads();
    }

    // Epilogue. lane holds sim[rbase+wm+i*16+quad*4+r][cbase+wn+j*16+l16].
    float* sL = (float*)As;                         // [256]
    unsigned long long* sP = (unsigned long long*)(As + 1024);  // [256]
    float se_v[4][4]; unsigned long long pk_v[4][4];
    #pragma unroll
    for (int i = 0; i < 4; ++i) {
        #pragma unroll
        for (int r = 0; r < 4; ++r) {
            float se = 0.f; float mx = -2.f; int mi = 0x7fffffff;
            #pragma unroll
            for (int j = 0; j < 4; ++j) {
                float v = acc[i][j][r];
                se += __expf(v * TEMP_INV);
                int col = cbase + wn + j * 16 + l16;
                if (v > mx || (v == mx && col < mi)) { mx = v; mi = col; }
            }
            #pragma unroll
            for (int off = 1; off < 16; off <<= 1) {
                se += __shfl_xor(se, off);
                float om = __shfl_xor(mx, off);
                int oi = __shfl_xor(mi, off);
                if (om > mx || (om == mx && oi < mi)) { mx = om; mi = oi; }
            }
            se_v[i][r] = se;
            pk_v[i][r] = ((unsigned long long)__float_as_uint(mx + 2.0f) << 32)
                         | (unsigned long long)(0xffffffffu - (unsigned)mi);
        }
    }
    // waves 0-3 (wn=0 half) publish; waves 4-7 merge + atomic.
    if (wave < 4 && l16 == 0) {
        #pragma unroll
        for (int i = 0; i < 4; ++i)
            #pragma unroll
            for (int r = 0; r < 4; ++r) {
                int rl = wm + i * 16 + quad * 4 + r;
                sL[rl] = se_v[i][r]; sP[rl] = pk_v[i][r];
            }
    }
    __syncthreads();
    if (wave >= 4 && l16 == 0) {
        #pragma unroll
        for (int i = 0; i < 4; ++i)
            #pragma unroll
            for (int r = 0; r < 4; ++r) {
                int rl = wm + i * 16 + quad * 4 + r;
                float se = se_v[i][r] + sL[rl];
                unsigned long long pk = pk_v[i][r];
                unsigned long long po = sP[rl];
                if (po > pk) pk = po;
                atomicAdd(&sumexp[rbase + rl], se);
                atomicMax(&pmax[rbase + rl], pk);
            }
    }
}

// ---------------- Phase 2: per-row loss + pos extraction -----------------------
__global__ void rowloss_kernel(const float* __restrict__ sumexp,
                               const unsigned long long* __restrict__ pmax,
                               int* __restrict__ pos, float* __restrict__ acc) {
    int r = blockIdx.x * 256 + threadIdx.x;
    unsigned long long p = pmax[r];
    float mx = __uint_as_float((unsigned)(p >> 32)) - 2.0f;
    pos[r] = (int)(0xffffffffu - (unsigned)(p & 0xffffffffu));
    float loss = logf(sumexp[r]) - mx * TEMP_INV;
    #pragma unroll
    for (int off = 1; off < 64; off <<= 1) loss += __shfl_xor(loss, off);
    __shared__ float red[4];
    if ((threadIdx.x & 63) == 0) red[threadIdx.x >> 6] = loss;
    __syncthreads();
    if (threadIdx.x == 0) atomicAdd(acc + 0, red[0] + red[1] + red[2] + red[3]);
}

// ---------------- Phase 3: contextual consistency ------------------------------
// 256 blocks x 4 waves, grid-stride over 8191 pairs, one atomic per block.
__global__ __launch_bounds__(256)
void ctx_kernel(const unsigned short* __restrict__ Tn,
                const int* __restrict__ pos, float* __restrict__ acc) {
    const int wave = threadIdx.x >> 6, lane = threadIdx.x & 63;
    const int wid = blockIdx.x * 4 + wave;          // 0..1023
    float s = 0.f;
    for (int g = wid; g < NROW - 1; g += 1024) {
        int ia = pos[g], ib = pos[g + 1];
        const short8* pa = (const short8*)(Tn + (size_t)ia * HDIM) + lane * 2;
        const short8* pb = (const short8*)(Tn + (size_t)ib * HDIM) + lane * 2;
        #pragma unroll
        for (int j = 0; j < 2; ++j) {
            short8 av = pa[j], bv = pb[j];
            #pragma unroll
            for (int e = 0; e < 8; ++e) s += bf2f(av[e]) * bf2f(bv[e]);
        }
    }
    #pragma unroll
    for (int off = 1; off < 64; off <<= 1) s += __shfl_xor(s, off);
    __shared__ float red[4];
    if (lane == 0) red[wave] = s;
    __syncthreads();
    if (threadIdx.x == 0) atomicAdd(acc + 1, red[0] + red[1] + red[2] + red[3]);
}

// ---------------- Phase 4: finalize -------------------------------------------
__global__ void fin_kernel(const float* __restrict__ acc, float* __restrict__ out) {
    out[0] = acc[0] / (float)NROW;
    out[1] = 1.0f - acc[1] / (float)(NROW - 1);
}

extern "C" void kernel_launch(void* const* d_in, const int* in_sizes, int n_in,
                              void* d_out, int out_size, void* d_ws, size_t ws_size,
                              hipStream_t stream) {
    const float* hs = (const float*)d_in[0];
    const float* ht = (const float*)d_in[1];
    char* ws = (char*)d_ws;
    unsigned short* Sn = (unsigned short*)(ws + SN_OFF);
    unsigned short* Tn = (unsigned short*)(ws + TN_OFF);
    int*   pos = (int*)(ws + POS_OFF);
    float* sumexp = (float*)(ws + SUM_OFF);
    unsigned long long* pmax = (unsigned long long*)(ws + PMX_OFF);
    float* acc = (float*)(ws + ACC_OFF);
    float* out = (float*)d_out;

    norm_kernel<<<4096, 256, 0, stream>>>(hs, ht, Sn, Tn, sumexp, pmax, acc);
    flash_kernel<<<2048, 512, 0, stream>>>(Sn, Tn, sumexp, pmax);
    rowloss_kernel<<<NROW / 256, 256, 0, stream>>>(sumexp, pmax, pos, acc);
    ctx_kernel<<<256, 256, 0, stream>>>(Tn, pos, acc);
    fin_kernel<<<1, 1, 0, stream>>>(acc, out);
}

// Round 6
// 254.947 us; speedup vs baseline: 6.1757x; 1.3290x over previous
//
#include <hip/hip_runtime.h>
#include <hip/hip_bf16.h>
#include <stdint.h>

// B=16,T=512,H=1024 -> N=M=8192 rows, H=1024.
// out[0] = mean_i [ log(sum_j exp(sim_ij/T)) - max_j sim_ij / T ]
// out[1] = 1 - mean_i dot(Tn[pos[i]], Tn[pos[i+1]])
// sim computed in fp8 e4m3 (MFMA 16x16x32_fp8_fp8, fp32 accumulate).
//
// fp8 data is stored in MFMA-fragment-tiled layout:
//   row r, k -> group g=r>>4, byte off = g*16384 + (k>>5)*512 + ((k&31)>>3)*128
//              + (r&15)*8 + (k&7)
// so one global_load_lds(1KB) is a straight contiguous copy and ds_read_b64
// at (chunk*512 + lane*8) yields exactly the A/B fragment for 16x16x32.

#define HDIM 1024
#define NROW 8192
#define TEMP_INV (1.0f / 0.07f)

typedef __attribute__((ext_vector_type(4))) float float4v;  // MFMA C/D
typedef __attribute__((ext_vector_type(2))) float float2v;

// ws layout (bytes)
#define SN_OFF   ((size_t)0)                        // 8 MB fp8 tiled S
#define TN_OFF   ((size_t)8388608)                  // 8 MB fp8 tiled T
#define POS_OFF  ((size_t)16777216)                 // 8192 int
#define SUM_OFF  (POS_OFF + 32768)                  // 8192 float sum-exp
#define PMX_OFF  (SUM_OFF + 32768)                  // 8192 u64 packed (max,~idx)
#define ACC_OFF  (PMX_OFF + 65536)                  // 2 floats

// async 16B global -> LDS (per-lane gptr; lane i lands at lds_base + i*16)
static __device__ __forceinline__ void gload_lds16(const void* gptr, void* lptr) {
    __builtin_amdgcn_global_load_lds(
        (const __attribute__((address_space(1))) void*)gptr,
        (__attribute__((address_space(3))) void*)(uintptr_t)(uint32_t)(uintptr_t)lptr,
        16, 0, 0);
}

// dot of 4 fp8 pairs packed in two dwords
static __device__ __forceinline__ float fp8dot4(unsigned a, unsigned b) {
    float2v al = __builtin_amdgcn_cvt_pk_f32_fp8((int)a, false);
    float2v ah = __builtin_amdgcn_cvt_pk_f32_fp8((int)a, true);
    float2v bl = __builtin_amdgcn_cvt_pk_f32_fp8((int)b, false);
    float2v bh = __builtin_amdgcn_cvt_pk_f32_fp8((int)b, true);
    return al[0]*bl[0] + al[1]*bl[1] + ah[0]*bh[0] + ah[1]*bh[1];
}

// ---------------- Phase 0: normalize -> fp8 e4m3, fragment-tiled ---------------
// Block = one 16-row group. Thread (r=t>>4, c=t&15) owns row r, k in [c*64,c*64+64).
__global__ __launch_bounds__(256)
void norm_kernel(const float* __restrict__ hs, const float* __restrict__ ht,
                 char* __restrict__ Sn, char* __restrict__ Tn,
                 float* __restrict__ sumexp, unsigned long long* __restrict__ pmax,
                 float* __restrict__ acc) {
    const int b = blockIdx.x;                       // 0..1023
    const int t = threadIdx.x;
    const int r = t >> 4, c = t & 15;
    const float* in;
    char* outg;
    if (b < 512) { in = hs + (size_t)(b * 16 + r) * HDIM;        outg = Sn + (size_t)b * 16384; }
    else         { in = ht + (size_t)((b - 512) * 16 + r) * HDIM; outg = Tn + (size_t)(b - 512) * 16384; }

    float4v v[16];
    float ss = 0.f;
    #pragma unroll
    for (int i = 0; i < 16; ++i) {
        v[i] = ((const float4v*)in)[c * 16 + i];
        ss += v[i][0]*v[i][0] + v[i][1]*v[i][1] + v[i][2]*v[i][2] + v[i][3]*v[i][3];
    }
    // reduce over the 16 threads sharing row r (lanes (r&3)*16 + c)
    #pragma unroll
    for (int off = 1; off < 16; off <<= 1) ss += __shfl_xor(ss, off);
    const float sc = 1.0f / fmaxf(sqrtf(ss), 1e-12f);

    // write 8 fragment pieces: (h=0,1: ks=c*2+h) x (quad=0..3), 8 bytes each
    #pragma unroll
    for (int h = 0; h < 2; ++h) {
        #pragma unroll
        for (int q = 0; q < 4; ++q) {
            const int vi = h * 8 + q * 2;           // float4 holding k = h*32+q*8 ..
            int d0 = __builtin_amdgcn_cvt_pk_fp8_f32(v[vi][0]*sc, v[vi][1]*sc, 0, false);
            d0     = __builtin_amdgcn_cvt_pk_fp8_f32(v[vi][2]*sc, v[vi][3]*sc, d0, true);
            int d1 = __builtin_amdgcn_cvt_pk_fp8_f32(v[vi+1][0]*sc, v[vi+1][1]*sc, 0, false);
            d1     = __builtin_amdgcn_cvt_pk_fp8_f32(v[vi+1][2]*sc, v[vi+1][3]*sc, d1, true);
            uint2 pk; pk.x = (unsigned)d0; pk.y = (unsigned)d1;
            *(uint2*)(outg + (c * 2 + h) * 512 + q * 128 + r * 8) = pk;
        }
    }

    if (b < 512 && t < 16) { sumexp[b * 16 + t] = 0.f; pmax[b * 16 + t] = 0ull; }
    if (b == 0 && t == 16) { acc[0] = 0.f; acc[1] = 0.f; }
}

// ---------------- Phase 1: multi-strip MFMA flash pass -------------------------
// Grid 512 = 32 row-tiles x 16 col-tiles. Block = 256 rows x 512 cols (4 strips
// of 128). 8 waves (4 row x 2 col), wave tile 64x64, 4x4 16x16x32_fp8 MFMAs.
// Per-strip epilogue merges (sumexp,max,argmax) into LDS state; one atomic set
// per block at the end. L3 traffic ~384 MB total (vs 1.57 GB in bf16/128-tile).
__global__ __launch_bounds__(512, 4)
void flash_kernel(const char* __restrict__ Sn, const char* __restrict__ Tn,
                  float* __restrict__ sumexp, unsigned long long* __restrict__ pmax) {
    __shared__ __align__(16) char As[16384];        // 16 groups x (2 ks x 512B)
    __shared__ __align__(16) char Bs[8192];         // 8 groups
    __shared__ float stSe[256];
    __shared__ unsigned long long stPk[256];
    const int t = threadIdx.x;
    const int wave = t >> 6, lane = t & 63;
    const int quad = lane >> 4, l16 = lane & 15;
    const int rbase  = (int)(blockIdx.x & 31) * 256;
    const int cbase0 = (int)(blockIdx.x >> 5) * 512;

    if (t < 256) { stSe[t] = 0.f; stPk[t] = 0ull; }

    const int wm = (wave & 3) * 64, wn = (wave >> 2) * 64;

    // per-lane staging pointers (contiguous 1KB per instr: lane*16)
    const char* gaBase0 = Sn + (size_t)(rbase / 16 + wave * 2 + 0) * 16384 + lane * 16;
    const char* gaBase1 = Sn + (size_t)(rbase / 16 + wave * 2 + 1) * 16384 + lane * 16;

    for (int s = 0; s < 4; ++s) {
        const int cbase = cbase0 + s * 128;
        const char* ga0 = gaBase0;
        const char* ga1 = gaBase1;
        const char* gb  = Tn + (size_t)(cbase / 16 + wave) * 16384 + lane * 16;

        float4v acc[4][4];
        #pragma unroll
        for (int i = 0; i < 4; ++i)
            #pragma unroll
            for (int j = 0; j < 4; ++j) acc[i][j] = (float4v){0.f, 0.f, 0.f, 0.f};

        for (int kb = 0; kb < 16; ++kb) {
            gload_lds16(ga0, As + (wave * 2 + 0) * 1024);
            gload_lds16(ga1, As + (wave * 2 + 1) * 1024);
            gload_lds16(gb,  Bs + wave * 1024);
            ga0 += 1024; ga1 += 1024; gb += 1024;
            __syncthreads();
            #pragma unroll
            for (int ks = 0; ks < 2; ++ks) {
                long af[4], bf[4];
                #pragma unroll
                for (int i = 0; i < 4; ++i)
                    af[i] = *(const long*)(As + ((wave & 3) * 4 + i) * 1024 + ks * 512 + lane * 8);
                #pragma unroll
                for (int j = 0; j < 4; ++j)
                    bf[j] = *(const long*)(Bs + ((wave >> 2) * 4 + j) * 1024 + ks * 512 + lane * 8);
                #pragma unroll
                for (int i = 0; i < 4; ++i)
                    #pragma unroll
                    for (int j = 0; j < 4; ++j)
                        acc[i][j] = __builtin_amdgcn_mfma_f32_16x16x32_fp8_fp8(af[i], bf[j], acc[i][j], 0, 0, 0);
            }
            __syncthreads();
        }

        // strip epilogue: lane holds sim[rbase+wm+i*16+quad*4+r][cbase+wn+j*16+l16]
        float* pbSe = (float*)Bs;
        unsigned long long* pbPk = (unsigned long long*)(Bs + 1024);
        float se_v[4][4]; unsigned long long pk_v[4][4];
        #pragma unroll
        for (int i = 0; i < 4; ++i) {
            #pragma unroll
            for (int r = 0; r < 4; ++r) {
                float se = 0.f; float mx = -2.f; int mi = 0x7fffffff;
                #pragma unroll
                for (int j = 0; j < 4; ++j) {
                    float v = acc[i][j][r];
                    se += __expf(v * TEMP_INV);
                    int col = cbase + wn + j * 16 + l16;
                    if (v > mx || (v == mx && col < mi)) { mx = v; mi = col; }
                }
                #pragma unroll
                for (int off = 1; off < 16; off <<= 1) {
                    se += __shfl_xor(se, off);
                    float om = __shfl_xor(mx, off);
                    int oi = __shfl_xor(mi, off);
                    if (om > mx || (om == mx && oi < mi)) { mx = om; mi = oi; }
                }
                se_v[i][r] = se;
                pk_v[i][r] = ((unsigned long long)__float_as_uint(mx + 2.0f) << 32)
                             | (unsigned long long)(0xffffffffu - (unsigned)mi);
            }
        }
        if (wave < 4 && l16 == 0) {
            #pragma unroll
            for (int i = 0; i < 4; ++i)
                #pragma unroll
                for (int r = 0; r < 4; ++r) {
                    int rl = wm + i * 16 + quad * 4 + r;
                    pbSe[rl] = se_v[i][r]; pbPk[rl] = pk_v[i][r];
                }
        }
        __syncthreads();
        if (wave >= 4 && l16 == 0) {
            #pragma unroll
            for (int i = 0; i < 4; ++i)
                #pragma unroll
                for (int r = 0; r < 4; ++r) {
                    int rl = wm + i * 16 + quad * 4 + r;
                    float se = se_v[i][r] + pbSe[rl];
                    unsigned long long pk = pk_v[i][r];
                    unsigned long long po = pbPk[rl];
                    if (po > pk) pk = po;
                    stSe[rl] += se;
                    if (pk > stPk[rl]) stPk[rl] = pk;
                }
        }
        __syncthreads();
    }

    if (t < 256) {
        atomicAdd(&sumexp[rbase + t], stSe[t]);
        atomicMax(&pmax[rbase + t], stPk[t]);
    }
}

// ---------------- Phase 2: per-row loss + pos extraction -----------------------
__global__ void rowloss_kernel(const float* __restrict__ sumexp,
                               const unsigned long long* __restrict__ pmax,
                               int* __restrict__ pos, float* __restrict__ acc) {
    int r = blockIdx.x * 256 + threadIdx.x;
    unsigned long long p = pmax[r];
    float mx = __uint_as_float((unsigned)(p >> 32)) - 2.0f;
    pos[r] = (int)(0xffffffffu - (unsigned)(p & 0xffffffffu));
    float loss = logf(sumexp[r]) - mx * TEMP_INV;
    #pragma unroll
    for (int off = 1; off < 64; off <<= 1) loss += __shfl_xor(loss, off);
    __shared__ float red[4];
    if ((threadIdx.x & 63) == 0) red[threadIdx.x >> 6] = loss;
    __syncthreads();
    if (threadIdx.x == 0) atomicAdd(acc + 0, red[0] + red[1] + red[2] + red[3]);
}

// ---------------- Phase 3: contextual consistency (fp8 tiled reads) ------------
__global__ __launch_bounds__(256)
void ctx_kernel(const char* __restrict__ Tn,
                const int* __restrict__ pos, float* __restrict__ acc) {
    const int wave = threadIdx.x >> 6, lane = threadIdx.x & 63;
    const int wid = blockIdx.x * 4 + wave;          // 0..1023
    float s = 0.f;
    for (int g = wid; g < NROW - 1; g += 1024) {
        int ia = pos[g], ib = pos[g + 1];
        #pragma unroll
        for (int h = 0; h < 2; ++h) {
            int p = lane + h * 64;                  // piece 0..127
            int off = (p >> 2) * 512 + (p & 3) * 128;
            uint2 va = *(const uint2*)(Tn + (size_t)(ia >> 4) * 16384 + off + (ia & 15) * 8);
            uint2 vb = *(const uint2*)(Tn + (size_t)(ib >> 4) * 16384 + off + (ib & 15) * 8);
            s += fp8dot4(va.x, vb.x);
            s += fp8dot4(va.y, vb.y);
        }
    }
    #pragma unroll
    for (int off = 1; off < 64; off <<= 1) s += __shfl_xor(s, off);
    __shared__ float red[4];
    if (lane == 0) red[wave] = s;
    __syncthreads();
    if (threadIdx.x == 0) atomicAdd(acc + 1, red[0] + red[1] + red[2] + red[3]);
}

// ---------------- Phase 4: finalize -------------------------------------------
__global__ void fin_kernel(const float* __restrict__ acc, float* __restrict__ out) {
    out[0] = acc[0] / (float)NROW;
    out[1] = 1.0f - acc[1] / (float)(NROW - 1);
}

extern "C" void kernel_launch(void* const* d_in, const int* in_sizes, int n_in,
                              void* d_out, int out_size, void* d_ws, size_t ws_size,
                              hipStream_t stream) {
    const float* hs = (const float*)d_in[0];
    const float* ht = (const float*)d_in[1];
    char* ws = (char*)d_ws;
    char* Sn = ws + SN_OFF;
    char* Tn = ws + TN_OFF;
    int*   pos = (int*)(ws + POS_OFF);
    float* sumexp = (float*)(ws + SUM_OFF);
    unsigned long long* pmax = (unsigned long long*)(ws + PMX_OFF);
    float* acc = (float*)(ws + ACC_OFF);
    float* out = (float*)d_out;

    norm_kernel<<<1024, 256, 0, stream>>>(hs, ht, Sn, Tn, sumexp, pmax, acc);
    flash_kernel<<<512, 512, 0, stream>>>(Sn, Tn, sumexp, pmax);
    rowloss_kernel<<<NROW / 256, 256, 0, stream>>>(sumexp, pmax, pos, acc);
    ctx_kernel<<<256, 256, 0, stream>>>(Tn, pos, acc);
    fin_kernel<<<1, 1, 0, stream>>>(acc, out);
}